// Round 7
// baseline (369.792 us; speedup 1.0000x reference)
//
#include <hip/hip_runtime.h>
#include <hip/hip_bf16.h>
#include <math.h>

typedef __attribute__((ext_vector_type(8))) short bx8;
typedef __attribute__((ext_vector_type(4))) short sx4;
typedef __attribute__((ext_vector_type(4))) float fx4;

#define D_   1024
#define H_   8
#define E_   16
#define HD_  128
#define I_   512
#define M8_  8192      // BS*L
#define T_   65536     // M8*H

__device__ inline float bf2f(short u) {
  unsigned int x = ((unsigned int)(unsigned short)u) << 16;
  return __builtin_bit_cast(float, x);
}
__device__ inline short f2bf(float f) {
  __hip_bfloat16 h = __float2bfloat16(f);
  return __builtin_bit_cast(short, h);
}

__device__ inline void gload_lds16(const void* g, void* l) {
  __builtin_amdgcn_global_load_lds(
      (const __attribute__((address_space(1))) void*)g,
      (__attribute__((address_space(3))) void*)l, 16, 0, 0);
}

__device__ inline fx4 mfma16(bx8 a, bx8 b, fx4 c) {
  return __builtin_amdgcn_mfma_f32_16x16x32_bf16(a, b, c, 0, 0, 0);
}

// exact-class GELU: erf via Abramowitz-Stegun 7.1.26 (abs err 1.5e-7)
__device__ inline float gelu_erf(float x) {
  float z = fabsf(x) * 0.70710678118654752f;
  float t = __builtin_amdgcn_rcpf(fmaf(0.3275911f, z, 1.f));
  float p = t * fmaf(t, fmaf(t, fmaf(t, fmaf(t, 1.061405429f, -1.453152027f),
                                     1.421413741f), -0.284496736f), 0.254829592f);
  float er = fmaf(-p, __expf(-z * z), 1.f);
  er = copysignf(er, x);
  return 0.5f * x * (1.f + er);
}

// ---------------- conversions ----------------

// batched transpose+convert: dst[b][c][r] = src[b][r][c]
__global__ __launch_bounds__(256) void tcvt(const float* __restrict__ src,
                                            __hip_bfloat16* __restrict__ dst,
                                            int R, int C) {
  __shared__ float tile[32][33];
  int tx = threadIdx.x & 31, ty = threadIdx.x >> 5;
  int r0 = blockIdx.y * 32, c0 = blockIdx.x * 32;
  const float* s = src + (size_t)blockIdx.z * R * C;
  __hip_bfloat16* d = dst + (size_t)blockIdx.z * R * C;
#pragma unroll
  for (int i = ty; i < 32; i += 8) tile[i][tx] = s[(size_t)(r0 + i) * C + c0 + tx];
  __syncthreads();
#pragma unroll
  for (int i = ty; i < 32; i += 8)
    d[(size_t)(c0 + i) * R + r0 + tx] = __float2bfloat16(tile[tx][i]);
}

// ---------------- routing (exact fp32 path) ----------------

// WreT[n][d] = sum_c Wm[d][(n>>4)*128+c] * emb[c][n&15]   (n = eta*16+e)
__global__ __launch_bounds__(128) void build_wre(const float* __restrict__ Wm,
                                                 const float* __restrict__ bm,
                                                 const float* __restrict__ emb,
                                                 float* __restrict__ WreT,
                                                 float* __restrict__ rbias) {
  __shared__ float wrow[1024];
  __shared__ float embs[2048];
  int tid = threadIdx.x;
  int d = blockIdx.x;
  for (int i = tid; i < 2048; i += 128) embs[i] = emb[i];
  for (int i = tid; i < 1024; i += 128) wrow[i] = Wm[(size_t)d * 1024 + i];
  __syncthreads();
  int eta = tid >> 4, e = tid & 15;
  float acc = 0.f;
  for (int c = 0; c < 128; ++c) acc = fmaf(wrow[eta * 128 + c], embs[c * 16 + e], acc);
  WreT[(size_t)tid * 1024 + d] = acc;
  if (blockIdx.x == 0) {
    float b = 0.f;
    for (int c = 0; c < 128; ++c) b = fmaf(bm[eta * 128 + c], embs[c * 16 + e], b);
    rbias[tid] = b;
  }
}

// fused: x->bf16 cast  +  logits = x @ WreT^T + rbias (fp32)  ->  top-2 -> lists
__global__ __launch_bounds__(256) void route_fused2(const float* __restrict__ x,
                                                    const float* __restrict__ WreT,
                                                    const float* __restrict__ rbias,
                                                    __hip_bfloat16* __restrict__ xb,
                                                    float* __restrict__ topw,
                                                    int* __restrict__ list,
                                                    int* __restrict__ cnt) {
  __shared__ float xs[16][64];     // 4 KiB
  __shared__ float wshT[128][68];  // 34 KiB (pad 68 -> balanced b128 reads)
  __shared__ float ls[16][129];    // 8.25 KiB
  __shared__ int lcnt[16];
  __shared__ int gbase[16];
  int tid = threadIdx.x;
  int rg = tid >> 6, cg = tid & 63;
  int row0 = blockIdx.x * 16;
  if (tid < 16) lcnt[tid] = 0;
  float acc[4][2];
#pragma unroll
  for (int i = 0; i < 4; ++i) { acc[i][0] = 0.f; acc[i][1] = 0.f; }

  for (int k0 = 0; k0 < 1024; k0 += 64) {
    __syncthreads();
    {  // stage x chunk (16 rows x 64 k) + write bf16 cast
      int i4 = tid * 4;
      int row = i4 >> 6, col = i4 & 63;
      float4 xv = *(const float4*)&x[(size_t)(row0 + row) * 1024 + k0 + col];
      *(float4*)&xs[row][col] = xv;
      sx4 o;
      o[0] = f2bf(xv.x); o[1] = f2bf(xv.y); o[2] = f2bf(xv.z); o[3] = f2bf(xv.w);
      *(sx4*)((short*)xb + (size_t)(row0 + row) * 1024 + k0 + col) = o;
    }
#pragma unroll
    for (int j = 0; j < 8; ++j) {  // stage WreT chunk: [128 n][64 k] (2048 float4s)
      int idx = tid + j * 256;
      int n = idx >> 4, kq = (idx & 15) * 4;
      *(float4*)&wshT[n][kq] = *(const float4*)&WreT[(size_t)n * 1024 + k0 + kq];
    }
    __syncthreads();
#pragma unroll 4
    for (int d4 = 0; d4 < 64; d4 += 4) {
      float4 w0 = *(const float4*)&wshT[cg][d4];
      float4 w1 = *(const float4*)&wshT[cg + 64][d4];
#pragma unroll
      for (int rr = 0; rr < 4; ++rr) {
        float4 xv = *(const float4*)&xs[rg * 4 + rr][d4];
        acc[rr][0] = fmaf(xv.x, w0.x, acc[rr][0]);
        acc[rr][0] = fmaf(xv.y, w0.y, acc[rr][0]);
        acc[rr][0] = fmaf(xv.z, w0.z, acc[rr][0]);
        acc[rr][0] = fmaf(xv.w, w0.w, acc[rr][0]);
        acc[rr][1] = fmaf(xv.x, w1.x, acc[rr][1]);
        acc[rr][1] = fmaf(xv.y, w1.y, acc[rr][1]);
        acc[rr][1] = fmaf(xv.z, w1.z, acc[rr][1]);
        acc[rr][1] = fmaf(xv.w, w1.w, acc[rr][1]);
      }
    }
  }
  float rb0 = rbias[cg], rb1 = rbias[cg + 64];
#pragma unroll
  for (int rr = 0; rr < 4; ++rr) {
    ls[rg * 4 + rr][cg] = acc[rr][0] + rb0;
    ls[rg * 4 + rr][cg + 64] = acc[rr][1] + rb1;
  }
  __syncthreads();

  int i1 = 0, i2 = 0, lp1 = 0, lp2 = 0, s = 0;
  if (tid < 128) {
    int lr = tid >> 3, eta = tid & 7;
    s = (row0 + lr) * 8 + eta;
    float v[16];
#pragma unroll
    for (int e = 0; e < 16; ++e) v[e] = ls[lr][eta * 16 + e];
    float v1 = -1e30f, v2 = -1e30f;
#pragma unroll
    for (int e = 0; e < 16; ++e) {
      float val = v[e];
      if (val > v1) { v2 = v1; i2 = i1; v1 = val; i1 = e; }
      else if (val > v2) { v2 = val; i2 = e; }
    }
    float sum = 0.f;
#pragma unroll
    for (int e = 0; e < 16; ++e) sum += expf(v[e] - v1);
    topw[(size_t)2 * s + 0] = 1.0f / sum;
    topw[(size_t)2 * s + 1] = expf(v2 - v1) / sum;
    lp1 = atomicAdd(&lcnt[i1], 1);
    lp2 = atomicAdd(&lcnt[i2], 1);
  }
  __syncthreads();
  if (tid < 16) gbase[tid] = atomicAdd(&cnt[tid], lcnt[tid]);
  __syncthreads();
  if (tid < 128) {
    list[(size_t)i1 * T_ + gbase[i1] + lp1] = 2 * s;
    list[(size_t)i2 * T_ + gbase[i2] + lp2] = 2 * s + 1;
  }
}

// 128-row tile bases per expert
__global__ void prefix_k(const int* __restrict__ cnt, int* __restrict__ tileBase) {
  if (threadIdx.x == 0 && blockIdx.x == 0) {
    int s = 0;
#pragma unroll
    for (int e = 0; e < 16; ++e) { tileBase[e] = s; s += (cnt[e] + 127) >> 7; }
    tileBase[16] = s;
  }
}

// ---------------- bf16 MFMA GEMM: C = A @ BT^T (+bias), BT is [N][K] ----------------

template <int OUTF32>
__global__ __launch_bounds__(256) void gemm_bt(const __hip_bfloat16* __restrict__ A,
                                               const __hip_bfloat16* __restrict__ BT,
                                               const float* __restrict__ bias,
                                               void* __restrict__ Cout,
                                               int M, int N, int Kd) {
  __shared__ __hip_bfloat16 As[128 * 64];
  __shared__ __hip_bfloat16 Bs[128 * 64];
  int tid = threadIdx.x;
  int lane = tid & 63, w = tid >> 6;
  int nbn = N >> 7;
  int cpx = gridDim.x >> 3;
  int swz = (blockIdx.x & 7) * cpx + (blockIdx.x >> 3);
  int bm = swz / nbn, bn = swz % nbn;
  int wm = w >> 1, wn = w & 1;
  int r = lane & 15, g = lane >> 4;
  const fx4 fz = {0.f, 0.f, 0.f, 0.f};
  fx4 acc[4][4];
#pragma unroll
  for (int m = 0; m < 4; ++m)
#pragma unroll
    for (int n = 0; n < 4; ++n) acc[m][n] = fz;
  const short* AsS = (const short*)As;
  const short* BsS = (const short*)Bs;
  for (int k0 = 0; k0 < Kd; k0 += 64) {
    __syncthreads();
#pragma unroll
    for (int i = 0; i < 4; ++i) {
      int c = i * 256 + w * 64 + lane;
      int row = c >> 3, ko = (c & 7) * 8;
      gload_lds16(A + (size_t)(bm * 128 + row) * Kd + k0 + ko,
                  (void*)(As + (size_t)(i * 256 + w * 64) * 8));
    }
#pragma unroll
    for (int i = 0; i < 4; ++i) {
      int c = i * 256 + w * 64 + lane;
      int row = c >> 3, ko = (c & 7) * 8;
      gload_lds16(BT + (size_t)(bn * 128 + row) * Kd + k0 + ko,
                  (void*)(Bs + (size_t)(i * 256 + w * 64) * 8));
    }
    __syncthreads();
#pragma unroll
    for (int kb = 0; kb < 2; ++kb) {
      bx8 af[4], bfr[4];
#pragma unroll
      for (int m = 0; m < 4; ++m)
        af[m] = *(const bx8*)(AsS + (wm * 64 + m * 16 + r) * 64 + kb * 32 + g * 8);
#pragma unroll
      for (int n = 0; n < 4; ++n)
        bfr[n] = *(const bx8*)(BsS + (wn * 64 + n * 16 + r) * 64 + kb * 32 + g * 8);
#pragma unroll
      for (int m = 0; m < 4; ++m)
#pragma unroll
        for (int n = 0; n < 4; ++n)
          acc[m][n] = mfma16(af[m], bfr[n], acc[m][n]);
    }
  }
#pragma unroll
  for (int n = 0; n < 4; ++n) {
    int col = bn * 128 + wn * 64 + n * 16 + r;
    float bv = bias[col];
#pragma unroll
    for (int m = 0; m < 4; ++m) {
      int rowb = bm * 128 + wm * 64 + m * 16 + g * 4;
#pragma unroll
      for (int ri = 0; ri < 4; ++ri) {
        float val = acc[m][n][ri] + bv;
        if (OUTF32) ((float*)Cout)[(size_t)(rowb + ri) * N + col] = val;
        else ((__hip_bfloat16*)Cout)[(size_t)(rowb + ri) * N + col] = __float2bfloat16(val);
      }
    }
  }
}

// ---------------- fused per-expert MLP v4 ----------------
// 128 rows/block, 4 waves x 32 rows (2 token fragments/wave in regs).
// W1 double-buffered; W2/W1-next DMA issued BEFORE GEMM1 so latency hides
// under GEMM1+GELU. LDS exactly 64 KiB -> 2 blocks/CU.

__global__ __launch_bounds__(256, 2) void expert_mlp4(
    const __hip_bfloat16* __restrict__ h,
    const __hip_bfloat16* __restrict__ W1T,   // [E][512 i][128 d]
    const __hip_bfloat16* __restrict__ W2T,   // [E][128 o][512 i]
    const float* __restrict__ b1,
    const float* __restrict__ b2,
    const float* __restrict__ topw,
    const int* __restrict__ list,
    const int* __restrict__ cnt,
    const int* __restrict__ tileBase,
    __hip_bfloat16* __restrict__ eo) {
  int b = blockIdx.x;
  if (b >= tileBase[16]) return;
  int e = 0;
#pragma unroll
  for (int i = 1; i < 16; ++i) e += (b >= tileBase[i]);
  int tile = b - tileBase[e];
  int cnt_e = cnt[e];
  int base = tile * 128;

  __shared__ short W1c[2][64 * 128];  // 32 KiB, [64 i][128 d] swizzled
  __shared__ short W2c[128 * 64];     // 16 KiB, [128 o][64 i] swizzled
  __shared__ short Hc[4][32 * 64];    // 16 KiB, per-wave [32 t][64 i] swizzled

  int tid = threadIdx.x, lane = tid & 63, wv = tid >> 6;
  int r = lane & 15, g = lane >> 4;
  const int* liste = list + (size_t)e * T_;
  const short* hS = (const short*)h;

  // token fragments (B-operand) in registers: rows base + wv*32 + tm*16 + r
  bx8 af[2][4];
#pragma unroll
  for (int tm = 0; tm < 2; ++tm) {
    int idx = base + wv * 32 + tm * 16 + r;
    int p = (idx < cnt_e) ? liste[idx] : -1;
    const short* rp = hS + (size_t)((p >= 0) ? (p >> 1) : 0) * 128 + g * 8;
#pragma unroll
    for (int kb = 0; kb < 4; ++kb) af[tm][kb] = *(const bx8*)(rp + kb * 32);
  }

  const char* W1S = (const char*)(W1T + (size_t)e * I_ * HD_);
  const char* W2S = (const char*)(W2T + (size_t)e * HD_ * I_);
  const float* b1e = b1 + (size_t)e * I_;
  const float* b2e = b2 + (size_t)e * HD_;
  char* HcW = (char*)Hc[wv];

  // staging helpers (linear LDS dest, inverse-swizzled global source)
  auto stageW1 = [&](int buf, int c) {
#pragma unroll
    for (int j = 0; j < 4; ++j) {
      int row = wv * 16 + j * 4 + (lane >> 4);
      int u = lane & 15;
      gload_lds16(W1S + (size_t)(c * 64 + row) * 256 + ((u * 16) ^ ((row & 7) << 4)),
                  (char*)W1c[buf] + (wv * 16 + j * 4) * 256);
    }
  };
  auto stageW2 = [&](int c) {
#pragma unroll
    for (int j = 0; j < 4; ++j) {
      int row = wv * 32 + j * 8 + (lane >> 3);
      int u = lane & 7;
      gload_lds16(W2S + (size_t)row * 1024 + c * 128 + ((u * 16) ^ ((row & 7) << 4)),
                  (char*)W2c + (wv * 32 + j * 8) * 128);
    }
  };

  const fx4 fz = {0.f, 0.f, 0.f, 0.f};
  fx4 acc2[2][8];
#pragma unroll
  for (int tm = 0; tm < 2; ++tm)
#pragma unroll
    for (int n = 0; n < 8; ++n) acc2[tm][n] = fz;

  stageW1(0, 0);
  __syncthreads();

  for (int c = 0; c < 8; ++c) {
    int cur = c & 1;
    // issue next-phase DMA first (hides under GEMM1+GELU)
    stageW2(c);
    if (c < 7) stageW1(cur ^ 1, c + 1);

    // GEMM1 (swapped): D1[i][t], A = W1 rows, B = token frags
    fx4 acc1[4][2];
#pragma unroll
    for (int ib = 0; ib < 4; ++ib) { acc1[ib][0] = fz; acc1[ib][1] = fz; }
#pragma unroll
    for (int kb = 0; kb < 4; ++kb) {
#pragma unroll
      for (int ib = 0; ib < 4; ++ib) {
        int irow = ib * 16 + r;
        bx8 a = *(const bx8*)((const char*)W1c[cur] + irow * 256 +
                              ((kb * 64 + g * 16) ^ ((r & 7) << 4)));
        acc1[ib][0] = mfma16(a, af[0][kb], acc1[ib][0]);
        acc1[ib][1] = mfma16(a, af[1][kb], acc1[ib][1]);
      }
    }

    // GELU -> Hc (lane holds hmid[i=ib*16+g*4+ri][t=tm*16+r])
#pragma unroll
    for (int ib = 0; ib < 4; ++ib) {
      float4 b1v = *(const float4*)&b1e[c * 64 + ib * 16 + g * 4];
#pragma unroll
      for (int tm = 0; tm < 2; ++tm) {
        sx4 ov;
        ov[0] = f2bf(gelu_erf(acc1[ib][tm][0] + b1v.x));
        ov[1] = f2bf(gelu_erf(acc1[ib][tm][1] + b1v.y));
        ov[2] = f2bf(gelu_erf(acc1[ib][tm][2] + b1v.z));
        ov[3] = f2bf(gelu_erf(acc1[ib][tm][3] + b1v.w));
        int t = tm * 16 + r;
        *(sx4*)(HcW + t * 128 + ((ib * 32 + g * 8) ^ ((r & 7) << 4))) = ov;
      }
    }

    __syncthreads();  // drains DMA: W2c (and W1 next) staged

    // GEMM2: D2[t][o] += hmid[t][i] * W2T[o][i]
#pragma unroll
    for (int kb2 = 0; kb2 < 2; ++kb2) {
      bx8 ha0 = *(const bx8*)(HcW + r * 128 + ((kb2 * 64 + g * 16) ^ ((r & 7) << 4)));
      bx8 ha1 = *(const bx8*)(HcW + (16 + r) * 128 + ((kb2 * 64 + g * 16) ^ ((r & 7) << 4)));
#pragma unroll
      for (int ob = 0; ob < 8; ++ob) {
        bx8 wb = *(const bx8*)((const char*)W2c + (ob * 16 + r) * 128 +
                               ((kb2 * 64 + g * 16) ^ ((r & 7) << 4)));
        acc2[0][ob] = mfma16(ha0, wb, acc2[0][ob]);
        acc2[1][ob] = mfma16(ha1, wb, acc2[1][ob]);
      }
    }
    __syncthreads();  // W2c free for next chunk
  }

  // epilogue: acc2[tm][ob][ri] -> eo[row][ob*16+r], row = base+wv*32+tm*16+g*4+ri
#pragma unroll
  for (int tm = 0; tm < 2; ++tm) {
    int pid_ep[4];
    float wt_ep[4];
#pragma unroll
    for (int ri = 0; ri < 4; ++ri) {
      int idx = base + wv * 32 + tm * 16 + g * 4 + ri;
      int p = (idx < cnt_e) ? liste[idx] : -1;
      pid_ep[ri] = p;
      wt_ep[ri] = (p >= 0) ? topw[p] : 0.f;
    }
#pragma unroll
    for (int ob = 0; ob < 8; ++ob) {
      float b2v = b2e[ob * 16 + r];
#pragma unroll
      for (int ri = 0; ri < 4; ++ri) {
        int p = pid_ep[ri];
        if (p >= 0) {
          float v = (acc2[tm][ob][ri] + b2v) * wt_ep[ri];
          eo[(size_t)p * 128 + ob * 16 + r] = __float2bfloat16(v);
        }
      }
    }
  }
}

// comb[s][:] = eo[2s][:] + eo[2s+1][:]
__global__ __launch_bounds__(256) void combine_k(const __hip_bfloat16* __restrict__ eo,
                                                 __hip_bfloat16* __restrict__ comb) {
  int t = blockIdx.x * 256 + threadIdx.x;
  int s = t >> 4, oo = (t & 15) * 8;
  const short* eS = (const short*)eo;
  bx8 a = *(const bx8*)(eS + (size_t)s * 256 + oo);
  bx8 b = *(const bx8*)(eS + (size_t)s * 256 + 128 + oo);
  bx8 ov;
#pragma unroll
  for (int j = 0; j < 8; ++j) ov[j] = f2bf(bf2f(a[j]) + bf2f(b[j]));
  *(bx8*)((short*)comb + (size_t)s * 128 + oo) = ov;
}

// ---------------- host ----------------

extern "C" void kernel_launch(void* const* d_in, const int* in_sizes, int n_in,
                              void* d_out, int out_size, void* d_ws, size_t ws_size,
                              hipStream_t stream) {
  const float* x   = (const float*)d_in[0];
  const float* Wm  = (const float*)d_in[1];
  const float* bm  = (const float*)d_in[2];
  const float* emb = (const float*)d_in[3];
  const float* W1  = (const float*)d_in[4];
  const float* b1  = (const float*)d_in[5];
  const float* W2  = (const float*)d_in[6];
  const float* b2  = (const float*)d_in[7];
  const float* Wo  = (const float*)d_in[8];
  const float* bo  = (const float*)d_in[9];

  char* ws = (char*)d_ws;
  size_t off = 0;
  auto alloc = [&](size_t b) { size_t r = off; off += (b + 255) & ~(size_t)255; return r; };
  __hip_bfloat16* xb   = (__hip_bfloat16*)(ws + alloc((size_t)M8_ * D_ * 2));
  __hip_bfloat16* WmT  = (__hip_bfloat16*)(ws + alloc((size_t)D_ * D_ * 2));
  __hip_bfloat16* WoT  = (__hip_bfloat16*)(ws + alloc((size_t)D_ * D_ * 2));
  __hip_bfloat16* W1T  = (__hip_bfloat16*)(ws + alloc((size_t)E_ * HD_ * I_ * 2));
  __hip_bfloat16* W2T  = (__hip_bfloat16*)(ws + alloc((size_t)E_ * HD_ * I_ * 2));
  __hip_bfloat16* hb   = (__hip_bfloat16*)(ws + alloc((size_t)M8_ * D_ * 2));
  float* WreT   = (float*)(ws + alloc((size_t)128 * D_ * 4));
  float* rbias  = (float*)(ws + alloc(512));
  float* topw   = (float*)(ws + alloc((size_t)T_ * 2 * 4));
  int*   cnt    = (int*)(ws + alloc(256));
  int*   tileBase = (int*)(ws + alloc(256));
  int*   list   = (int*)(ws + alloc((size_t)E_ * T_ * 4));
  __hip_bfloat16* eo   = (__hip_bfloat16*)(ws + alloc((size_t)T_ * 2 * HD_ * 2));
  __hip_bfloat16* comb = (__hip_bfloat16*)(ws + alloc((size_t)M8_ * D_ * 2));

  hipMemsetAsync(cnt, 0, 256, stream);
  tcvt<<<dim3(32, 32, 1), 256, 0, stream>>>(Wm, WmT, 1024, 1024);
  tcvt<<<dim3(32, 32, 1), 256, 0, stream>>>(Wo, WoT, 1024, 1024);
  tcvt<<<dim3(16, 4, 16), 256, 0, stream>>>(W1, W1T, 128, 512);
  tcvt<<<dim3(4, 16, 16), 256, 0, stream>>>(W2, W2T, 512, 128);
  build_wre<<<1024, 128, 0, stream>>>(Wm, bm, emb, WreT, rbias);
  route_fused2<<<512, 256, 0, stream>>>(x, WreT, rbias, xb, topw, list, cnt);
  prefix_k<<<1, 32, 0, stream>>>(cnt, tileBase);
  gemm_bt<0><<<512, 256, 0, stream>>>(xb, WmT, bm, hb, M8_, D_, D_);
  expert_mlp4<<<1040, 256, 0, stream>>>(hb, W1T, W2T, b1, b2, topw, list, cnt,
                                        tileBase, eo);
  combine_k<<<4096, 256, 0, stream>>>(eo, comb);
  gemm_bt<1><<<512, 256, 0, stream>>>(comb, WoT, bo, d_out, M8_, D_, D_);
}